// Round 1
// baseline (681.367 us; speedup 1.0000x reference)
//
#include <hip/hip_runtime.h>
#include <math.h>

// Problem constants (from reference): x[B,T,C] fp32, W[1,4C], b[1] -> out[B,1]
constexpr int Bn = 2048;
constexpr int Tn = 8192;
constexpr int Cn = 8;
constexpr int THREADS = 256;
constexpr int NVEC = Tn * Cn / 4;  // float4s per batch row = 16384

// One block per batch row. Each thread strides float4s with stride 256 (even),
// so vec-index parity (j&1) is fixed per thread -> thread owns a fixed
// 4-channel group: channels 4*(tid&1)+k for k=0..3. 16 reg accumulators.
__global__ __launch_bounds__(THREADS) void feat_reduce_kernel(
    const float* __restrict__ x,
    const float* __restrict__ W,
    const float* __restrict__ bias,
    float* __restrict__ out)
{
    const int b   = blockIdx.x;
    const int tid = threadIdx.x;
    const float4* __restrict__ xb =
        reinterpret_cast<const float4*>(x + (size_t)b * Tn * Cn);

    float cnt[4]  = {0.f, 0.f, 0.f, 0.f};       // sum of (x>0)
    float amax[4] = {0.f, 0.f, 0.f, 0.f};       // max of (x>0) in {0,1}
    float lsum[4] = {0.f, 0.f, 0.f, 0.f};       // sum of log1p(x)
    float lmax[4] = {-INFINITY, -INFINITY, -INFINITY, -INFINITY};

    #pragma unroll 4
    for (int j = tid; j < NVEC; j += THREADS) {
        float4 v = xb[j];
        float e[4] = {v.x, v.y, v.z, v.w};
        #pragma unroll
        for (int k = 0; k < 4; ++k) {
            float xv  = e[k];
            float act = (xv > 0.0f) ? 1.0f : 0.0f;
            cnt[k]  += act;
            amax[k]  = fmaxf(amax[k], act);
            float l  = __logf(1.0f + xv);   // log1p for x in [0,1); fast approx OK
            lsum[k] += l;
            lmax[k]  = fmaxf(lmax[k], l);
        }
    }

    // Butterfly over strides 2..32: even lanes fold with even lanes, odd with
    // odd, so the two channel groups never mix. After this every lane holds
    // its group's full wave reduction.
    #pragma unroll
    for (int off = 2; off < 64; off <<= 1) {
        #pragma unroll
        for (int k = 0; k < 4; ++k) {
            cnt[k]  += __shfl_xor(cnt[k],  off);
            lsum[k] += __shfl_xor(lsum[k], off);
            amax[k]  = fmaxf(amax[k], __shfl_xor(amax[k], off));
            lmax[k]  = fmaxf(lmax[k], __shfl_xor(lmax[k], off));
        }
    }

    // Cross-wave combine: 4 waves x 2 groups x 16 stats.
    __shared__ float smem[4][2][16];
    const int wave = tid >> 6;
    const int lane = tid & 63;
    if (lane < 2) {
        #pragma unroll
        for (int k = 0; k < 4; ++k) {
            smem[wave][lane][k]      = amax[k];
            smem[wave][lane][4 + k]  = cnt[k];
            smem[wave][lane][8 + k]  = lmax[k];
            smem[wave][lane][12 + k] = lsum[k];
        }
    }
    __syncthreads();

    if (tid == 0) {
        float res = bias[0];
        #pragma unroll
        for (int g = 0; g < 2; ++g) {
            #pragma unroll
            for (int k = 0; k < 4; ++k) {
                float am = smem[0][g][k];
                float cn = smem[0][g][4 + k];
                float lm = smem[0][g][8 + k];
                float ls = smem[0][g][12 + k];
                #pragma unroll
                for (int w = 1; w < 4; ++w) {
                    am  = fmaxf(am, smem[w][g][k]);
                    cn += smem[w][g][4 + k];
                    lm  = fmaxf(lm, smem[w][g][8 + k]);
                    ls += smem[w][g][12 + k];
                }
                const int ch = 4 * g + k;
                // torch feature order per channel: [a_max, a_sum, l_max, l_mean]
                res += am * W[4 * ch + 0]
                     + cn * W[4 * ch + 1]
                     + lm * W[4 * ch + 2]
                     + (ls * (1.0f / (float)Tn)) * W[4 * ch + 3];
            }
        }
        out[b] = res;
    }
}

extern "C" void kernel_launch(void* const* d_in, const int* in_sizes, int n_in,
                              void* d_out, int out_size, void* d_ws, size_t ws_size,
                              hipStream_t stream) {
    const float* x    = (const float*)d_in[0];
    const float* W    = (const float*)d_in[1];
    const float* bias = (const float*)d_in[2];
    float* out        = (float*)d_out;

    feat_reduce_kernel<<<Bn, THREADS, 0, stream>>>(x, W, bias, out);
}

// Round 2
// 637.213 us; speedup vs baseline: 1.0693x; 1.0693x over previous
//
#include <hip/hip_runtime.h>
#include <math.h>

// Problem constants (from reference): x[B,T,C] fp32, W[1,4C], b[1] -> out[B,1]
constexpr int Bn = 2048;
constexpr int Tn = 8192;
constexpr int Cn = 8;
constexpr int THREADS = 256;
constexpr int NVEC = Tn * Cn / 4;                 // 16384 float4 per row
constexpr int BATCH = 4;                          // float4 loads in flight per thread
constexpr int OUTER = NVEC / (THREADS * BATCH);   // 16

typedef float vfloat4 __attribute__((ext_vector_type(4)));

// One block per batch row (256 KiB contiguous). Thread t touches float4
// indices j = t + s*256; parity(j) == parity(t), so each thread owns a fixed
// 4-channel group: channels 4*(t&1)+k. Per element we track only
//   cnt  = sum(x>0)          -> a_sum, and a_max = (cnt>0)
//   xmax = max(x)            -> l_max = log1p(xmax)   (log1p monotone)
//   l2s  = sum(log2(1+x))    -> l_mean = l2s * ln2 / T (ln2 folded at end)
__global__ __launch_bounds__(THREADS) void feat_reduce_kernel(
    const float* __restrict__ x,
    const float* __restrict__ W,
    const float* __restrict__ bias,
    float* __restrict__ out)
{
    const int b   = blockIdx.x;
    const int tid = threadIdx.x;
    const vfloat4* __restrict__ xb =
        reinterpret_cast<const vfloat4*>(x + (size_t)b * Tn * Cn);

    float cnt[4]  = {0.f, 0.f, 0.f, 0.f};
    float xmax[4] = {0.f, 0.f, 0.f, 0.f};   // x in [0,1): 0 is a safe identity
    float l2s[4]  = {0.f, 0.f, 0.f, 0.f};   // log2(1+x) >= 0

    for (int it = 0; it < OUTER; ++it) {
        vfloat4 v[BATCH];
        #pragma unroll
        for (int u = 0; u < BATCH; ++u)
            v[u] = __builtin_nontemporal_load(&xb[tid + (it * BATCH + u) * THREADS]);
        #pragma unroll
        for (int u = 0; u < BATCH; ++u) {
            #pragma unroll
            for (int k = 0; k < 4; ++k) {
                float xv = v[u][k];
                cnt[k]  += (xv > 0.0f) ? 1.0f : 0.0f;
                xmax[k]  = fmaxf(xmax[k], xv);
                l2s[k]  += __log2f(1.0f + xv);
            }
        }
    }

    // Butterfly over strides 2..32: parity groups (channel sets) never mix.
    #pragma unroll
    for (int off = 2; off < 64; off <<= 1) {
        #pragma unroll
        for (int k = 0; k < 4; ++k) {
            cnt[k]  += __shfl_xor(cnt[k],  off);
            l2s[k]  += __shfl_xor(l2s[k],  off);
            xmax[k]  = fmaxf(xmax[k], __shfl_xor(xmax[k], off));
        }
    }

    // Cross-wave combine: 4 waves x 2 groups x 12 stats.
    __shared__ float smem[4][2][12];
    const int wave = tid >> 6;
    const int lane = tid & 63;
    if (lane < 2) {
        #pragma unroll
        for (int k = 0; k < 4; ++k) {
            smem[wave][lane][k]     = cnt[k];
            smem[wave][lane][4 + k] = xmax[k];
            smem[wave][lane][8 + k] = l2s[k];
        }
    }
    __syncthreads();

    if (tid == 0) {
        const float LN2 = 0.69314718055994530942f;
        float res = bias[0];
        #pragma unroll
        for (int g = 0; g < 2; ++g) {
            #pragma unroll
            for (int k = 0; k < 4; ++k) {
                float cn = smem[0][g][k];
                float xm = smem[0][g][4 + k];
                float ls = smem[0][g][8 + k];
                #pragma unroll
                for (int w = 1; w < 4; ++w) {
                    cn += smem[w][g][k];
                    xm  = fmaxf(xm, smem[w][g][4 + k]);
                    ls += smem[w][g][8 + k];
                }
                const int ch = 4 * g + k;
                const float am = (cn > 0.0f) ? 1.0f : 0.0f;
                const float lm = logf(1.0f + xm);
                const float lmean = ls * (LN2 / (float)Tn);
                // torch feature order per channel: [a_max, a_sum, l_max, l_mean]
                res += am * W[4 * ch + 0]
                     + cn * W[4 * ch + 1]
                     + lm * W[4 * ch + 2]
                     + lmean * W[4 * ch + 3];
            }
        }
        out[b] = res;
    }
}

extern "C" void kernel_launch(void* const* d_in, const int* in_sizes, int n_in,
                              void* d_out, int out_size, void* d_ws, size_t ws_size,
                              hipStream_t stream) {
    const float* x    = (const float*)d_in[0];
    const float* W    = (const float*)d_in[1];
    const float* bias = (const float*)d_in[2];
    float* out        = (float*)d_out;

    feat_reduce_kernel<<<Bn, THREADS, 0, stream>>>(x, W, bias, out);
}